// Round 1
// baseline (671.334 us; speedup 1.0000x reference)
//
#include <hip/hip_runtime.h>

// ---------------------------------------------------------------------------
// MultiHeadedDotProductSelfAttention: B=2, S=2048, D=2048, H=16, dh=128
// Strategy: fp32 -> bf16 cast; bf16 MFMA GEMMs (m97-style 128^2 tile, BK=32,
// global_load_lds w=16); flash attention (QBLK=64, KVBLK=32, online softmax).
// ---------------------------------------------------------------------------

typedef __attribute__((ext_vector_type(8))) short bfx8;
typedef __attribute__((ext_vector_type(4))) float f32x4;

#define TO_GLOBAL(p) ((const __attribute__((address_space(1))) void*)(p))
#define TO_LDS(p)    ((__attribute__((address_space(3))) void*)(p))

__device__ __forceinline__ unsigned short f2bf(float f) {
    unsigned int u = __float_as_uint(f);
    u += 0x7FFFu + ((u >> 16) & 1u);          // round-to-nearest-even
    return (unsigned short)(u >> 16);
}

__device__ __forceinline__ void store_out(unsigned short* p, float v) { *p = f2bf(v); }
__device__ __forceinline__ void store_out(float* p, float v) { *p = v; }

// ---------------------------------------------------------------- cast kernel
__global__ void cast_bf16_kernel(const float* __restrict__ x,
                                 unsigned short* __restrict__ y, int n4) {
    int i = blockIdx.x * blockDim.x + threadIdx.x;
    int st = gridDim.x * blockDim.x;
    for (; i < n4; i += st) {
        float4 v = reinterpret_cast<const float4*>(x)[i];
        ushort4 o;
        o.x = f2bf(v.x); o.y = f2bf(v.y); o.z = f2bf(v.z); o.w = f2bf(v.w);
        reinterpret_cast<ushort4*>(y)[i] = o;
    }
}

// ------------------------------------------------------- GEMM: C = (A*B^T+b)*s
// A: [M][K] bf16 row-major, Bw: [N][K] bf16 row-major (i.e. B^T input),
// bias: [N] fp32, C: [M][N] (bf16 or fp32). 128x128 tile, BK=32, 4 waves.
template <typename OUT>
__global__ __launch_bounds__(256) void gemm_bt(
    const unsigned short* __restrict__ A, const unsigned short* __restrict__ Bw,
    const float* __restrict__ bias, OUT* __restrict__ C,
    int M, int N, int K, float scale) {
    __shared__ __align__(16) unsigned short Ash[128 * 32];
    __shared__ __align__(16) unsigned short Bsh[128 * 32];

    const int tid  = threadIdx.x;
    const int lane = tid & 63;
    const int w    = tid >> 6;
    const int g    = lane >> 4;
    const int l15  = lane & 15;
    const int m0   = blockIdx.y * 128;
    const int n0   = blockIdx.x * 128;
    const int wm   = (w >> 1) * 64;
    const int wn   = (w & 1) * 64;

    f32x4 acc[4][4];
#pragma unroll
    for (int i = 0; i < 4; i++)
#pragma unroll
        for (int j = 0; j < 4; j++) acc[i][j] = (f32x4){0.f, 0.f, 0.f, 0.f};

    const int c0 = tid, c1 = tid + 256;
    const int rowA0 = c0 >> 2, colA0 = (c0 & 3) * 8;
    const int rowA1 = c1 >> 2, colA1 = (c1 & 3) * 8;

    for (int k0 = 0; k0 < K; k0 += 32) {
        __syncthreads();
        __builtin_amdgcn_global_load_lds(TO_GLOBAL(A + (size_t)(m0 + rowA0) * K + k0 + colA0),
                                         TO_LDS(&Ash[c0 * 8]), 16, 0, 0);
        __builtin_amdgcn_global_load_lds(TO_GLOBAL(A + (size_t)(m0 + rowA1) * K + k0 + colA1),
                                         TO_LDS(&Ash[c1 * 8]), 16, 0, 0);
        __builtin_amdgcn_global_load_lds(TO_GLOBAL(Bw + (size_t)(n0 + rowA0) * K + k0 + colA0),
                                         TO_LDS(&Bsh[c0 * 8]), 16, 0, 0);
        __builtin_amdgcn_global_load_lds(TO_GLOBAL(Bw + (size_t)(n0 + rowA1) * K + k0 + colA1),
                                         TO_LDS(&Bsh[c1 * 8]), 16, 0, 0);
        __syncthreads();

        bfx8 af[4], bfr[4];
#pragma unroll
        for (int mi = 0; mi < 4; mi++)
            af[mi] = *reinterpret_cast<const bfx8*>(&Ash[(wm + mi * 16 + l15) * 32 + g * 8]);
#pragma unroll
        for (int ni = 0; ni < 4; ni++)
            bfr[ni] = *reinterpret_cast<const bfx8*>(&Bsh[(wn + ni * 16 + l15) * 32 + g * 8]);
#pragma unroll
        for (int mi = 0; mi < 4; mi++)
#pragma unroll
            for (int ni = 0; ni < 4; ni++)
                acc[mi][ni] = __builtin_amdgcn_mfma_f32_16x16x32_bf16(af[mi], bfr[ni],
                                                                     acc[mi][ni], 0, 0, 0);
    }

#pragma unroll
    for (int mi = 0; mi < 4; mi++) {
#pragma unroll
        for (int ni = 0; ni < 4; ni++) {
            const int col = n0 + wn + ni * 16 + l15;
            const float bv = bias[col];
#pragma unroll
            for (int r = 0; r < 4; r++) {
                const int row = m0 + wm + mi * 16 + g * 4 + r;
                store_out(&C[(size_t)row * N + col], (acc[mi][ni][r] + bv) * scale);
            }
        }
    }
}

// ------------------------------------------------------------ flash attention
// Q,K,V,O: [B=2][S=2048][H=16][dh=128] bf16. Causal. Per block: 4 waves,
// QBLK=64 (16 q-rows/wave), KVBLK=32. Online softmax, P via per-wave LDS.
#define SLEN 2048
#define DMODEL 2048

__global__ __launch_bounds__(256) void attn_kernel(
    const unsigned short* __restrict__ Q, const unsigned short* __restrict__ Kp,
    const unsigned short* __restrict__ Vp, unsigned short* __restrict__ O) {
    __shared__ __align__(16) unsigned short Ksh[32 * 128];   // XOR-swizzled rows
    __shared__ __align__(16) unsigned short Vsh[128 * 40];   // transposed, padded
    __shared__ __align__(16) unsigned short Psh[4 * 16 * 32];

    const int tid  = threadIdx.x;
    const int lane = tid & 63;
    const int w    = tid >> 6;
    const int g    = lane >> 4;
    const int l15  = lane & 15;
    const int bh   = blockIdx.y;
    const int b    = bh >> 4, h = bh & 15;
    const int q0   = (gridDim.x - 1 - blockIdx.x) * 64;  // heavy tiles dispatch first

    const size_t bhbase = (size_t)b * SLEN * DMODEL + (size_t)h * 128;

    // Q fragments held in registers (16 q-rows x 128 d per wave)
    const int qrow = q0 + w * 16 + l15;
    bfx8 qf[4];
#pragma unroll
    for (int c = 0; c < 4; c++)
        qf[c] = *reinterpret_cast<const bfx8*>(Q + bhbase + (size_t)qrow * DMODEL + c * 32 + g * 8);

    f32x4 oacc[8];
#pragma unroll
    for (int i = 0; i < 8; i++) oacc[i] = (f32x4){0.f, 0.f, 0.f, 0.f};
    float m_run[4] = {-1e30f, -1e30f, -1e30f, -1e30f};
    float l_run[4] = {0.f, 0.f, 0.f, 0.f};

    const int wq0 = q0 + w * 16;
    const int nkv = q0 / 32 + 2;

    for (int t = 0; t < nkv; t++) {
        const int kbase = t * 32;
        // ---- stage K (swizzled) and V (transposed) into LDS
#pragma unroll
        for (int j = 0; j < 2; j++) {
            const int c = tid + 256 * j;
            const int row = c >> 4, col8 = c & 15;
            bfx8 kv = *reinterpret_cast<const bfx8*>(
                Kp + bhbase + (size_t)(kbase + row) * DMODEL + col8 * 8);
            *reinterpret_cast<bfx8*>(&Ksh[row * 128 + ((col8 ^ (row & 7)) * 8)]) = kv;
            bfx8 vv = *reinterpret_cast<const bfx8*>(
                Vp + bhbase + (size_t)(kbase + row) * DMODEL + col8 * 8);
#pragma unroll
            for (int ii = 0; ii < 8; ii++)
                Vsh[(col8 * 8 + ii) * 40 + row] = (unsigned short)vv[ii];
        }
        __syncthreads();

        if (kbase <= wq0 + 15) {
            // ---- S = Q K^T  (two 16-wide key tiles)
            f32x4 sacc[2];
            sacc[0] = (f32x4){0.f, 0.f, 0.f, 0.f};
            sacc[1] = (f32x4){0.f, 0.f, 0.f, 0.f};
#pragma unroll
            for (int kt = 0; kt < 2; kt++) {
                const int krow = kt * 16 + l15;
                const int sw = krow & 7;
#pragma unroll
                for (int c = 0; c < 4; c++) {
                    bfx8 kf = *reinterpret_cast<const bfx8*>(
                        &Ksh[krow * 128 + (((c * 4 + g) ^ sw) * 8)]);
                    sacc[kt] = __builtin_amdgcn_mfma_f32_16x16x32_bf16(qf[c], kf, sacc[kt], 0, 0, 0);
                }
            }
            // ---- causal mask (only tiles straddling the diagonal)
            if (kbase + 31 > wq0) {
#pragma unroll
                for (int kt = 0; kt < 2; kt++) {
                    const int kpos = kbase + kt * 16 + l15;
#pragma unroll
                    for (int r = 0; r < 4; r++) {
                        if (kpos > wq0 + g * 4 + r) sacc[kt][r] = -1e30f;
                    }
                }
            }
            // ---- online softmax (row = g*4+r, 16 lanes hold the 16 key cols)
#pragma unroll
            for (int r = 0; r < 4; r++) {
                float mx = fmaxf(sacc[0][r], sacc[1][r]);
#pragma unroll
                for (int s = 1; s < 16; s <<= 1) mx = fmaxf(mx, __shfl_xor(mx, s));
                const float mnew = fmaxf(m_run[r], mx);
                const float corr = __expf(m_run[r] - mnew);
                const float p0 = __expf(sacc[0][r] - mnew);
                const float p1 = __expf(sacc[1][r] - mnew);
                float ps = p0 + p1;
#pragma unroll
                for (int s = 1; s < 16; s <<= 1) ps += __shfl_xor(ps, s);
                m_run[r] = mnew;
                l_run[r] = l_run[r] * corr + ps;
                const int ql = g * 4 + r;
                Psh[w * 512 + ql * 32 + l15]      = f2bf(p0);
                Psh[w * 512 + ql * 32 + 16 + l15] = f2bf(p1);
#pragma unroll
                for (int ni = 0; ni < 8; ni++) oacc[ni][r] *= corr;
            }
            // ---- O += P V
            bfx8 pa = *reinterpret_cast<const bfx8*>(&Psh[w * 512 + l15 * 32 + g * 8]);
#pragma unroll
            for (int ni = 0; ni < 8; ni++) {
                bfx8 vb = *reinterpret_cast<const bfx8*>(&Vsh[(ni * 16 + l15) * 40 + g * 8]);
                oacc[ni] = __builtin_amdgcn_mfma_f32_16x16x32_bf16(pa, vb, oacc[ni], 0, 0, 0);
            }
        }
        __syncthreads();
    }

    // ---- normalize + store
#pragma unroll
    for (int r = 0; r < 4; r++) {
        const float inv = 1.0f / l_run[r];
        const int q = wq0 + g * 4 + r;
#pragma unroll
        for (int ni = 0; ni < 8; ni++)
            O[bhbase + (size_t)q * DMODEL + ni * 16 + l15] = f2bf(oacc[ni][r] * inv);
    }
}

// ---------------------------------------------------------------------------
extern "C" void kernel_launch(void* const* d_in, const int* in_sizes, int n_in,
                              void* d_out, int out_size, void* d_ws, size_t ws_size,
                              hipStream_t stream) {
    const float* X  = (const float*)d_in[0];
    const float* Wq = (const float*)d_in[1];
    const float* bq = (const float*)d_in[2];
    const float* Wk = (const float*)d_in[3];
    const float* bk = (const float*)d_in[4];
    const float* Wv = (const float*)d_in[5];
    const float* bv = (const float*)d_in[6];
    const float* Wo = (const float*)d_in[7];
    const float* bo = (const float*)d_in[8];
    float* out = (float*)d_out;

    // workspace layout (bf16 elements): Q | K | V | X(->attn O) | Wstage
    unsigned short* ws  = (unsigned short*)d_ws;
    unsigned short* Qb  = ws;
    unsigned short* Kb  = ws + 8388608;
    unsigned short* Vb  = ws + 16777216;
    unsigned short* XOb = ws + 25165824;   // X bf16, reused as attention output
    unsigned short* Wb  = ws + 33554432;   // 4194304-elem weight staging

    const float qk_scale = 0.29730177875068026f;  // 128^(-1/4)

    const dim3 cb(256);
    const dim3 gg(16, 32), gb(256);

    cast_bf16_kernel<<<dim3(2048), cb, 0, stream>>>(X, XOb, 2097152);

    cast_bf16_kernel<<<dim3(1024), cb, 0, stream>>>(Wq, Wb, 1048576);
    gemm_bt<unsigned short><<<gg, gb, 0, stream>>>(XOb, Wb, bq, Qb, 4096, 2048, 2048, qk_scale);

    cast_bf16_kernel<<<dim3(1024), cb, 0, stream>>>(Wk, Wb, 1048576);
    gemm_bt<unsigned short><<<gg, gb, 0, stream>>>(XOb, Wb, bk, Kb, 4096, 2048, 2048, qk_scale);

    cast_bf16_kernel<<<dim3(1024), cb, 0, stream>>>(Wv, Wb, 1048576);
    gemm_bt<unsigned short><<<gg, gb, 0, stream>>>(XOb, Wb, bv, Vb, 4096, 2048, 2048, 1.0f);

    attn_kernel<<<dim3(32, 32), gb, 0, stream>>>(Qb, Kb, Vb, XOb);

    cast_bf16_kernel<<<dim3(1024), cb, 0, stream>>>(Wo, Wb, 1048576);
    gemm_bt<float><<<gg, gb, 0, stream>>>(XOb, Wb, bo, out, 4096, 2048, 2048, 1.0f);
}

// Round 2
// 528.374 us; speedup vs baseline: 1.2706x; 1.2706x over previous
//
#include <hip/hip_runtime.h>

// ---------------------------------------------------------------------------
// MultiHeadedDotProductSelfAttention: B=2, S=2048, D=2048, H=16, dh=128
// R1: attention reads K/V directly from global (L2-resident per head),
// V pre-transposed to [bh][dh][s]; no barriers in the attn loop; KVBLK=64.
// ---------------------------------------------------------------------------

typedef __attribute__((ext_vector_type(8))) short bfx8;
typedef __attribute__((ext_vector_type(4))) float f32x4;

#define TO_GLOBAL(p) ((const __attribute__((address_space(1))) void*)(p))
#define TO_LDS(p)    ((__attribute__((address_space(3))) void*)(p))

__device__ __forceinline__ unsigned short f2bf(float f) {
    unsigned int u = __float_as_uint(f);
    u += 0x7FFFu + ((u >> 16) & 1u);          // round-to-nearest-even
    return (unsigned short)(u >> 16);
}

__device__ __forceinline__ void store_out(unsigned short* p, float v) { *p = f2bf(v); }
__device__ __forceinline__ void store_out(float* p, float v) { *p = v; }

// ---------------------------------------------------------------- cast kernel
__global__ void cast_bf16_kernel(const float* __restrict__ x,
                                 unsigned short* __restrict__ y, int n4) {
    int i = blockIdx.x * blockDim.x + threadIdx.x;
    int st = gridDim.x * blockDim.x;
    for (; i < n4; i += st) {
        float4 v = reinterpret_cast<const float4*>(x)[i];
        ushort4 o;
        o.x = f2bf(v.x); o.y = f2bf(v.y); o.z = f2bf(v.z); o.w = f2bf(v.w);
        reinterpret_cast<ushort4*>(y)[i] = o;
    }
}

// ------------------------------------------------------- GEMM: C = (A*B^T+b)*s
template <typename OUT>
__global__ __launch_bounds__(256) void gemm_bt(
    const unsigned short* __restrict__ A, const unsigned short* __restrict__ Bw,
    const float* __restrict__ bias, OUT* __restrict__ C,
    int M, int N, int K, float scale) {
    __shared__ __align__(16) unsigned short Ash[128 * 32];
    __shared__ __align__(16) unsigned short Bsh[128 * 32];

    const int tid  = threadIdx.x;
    const int lane = tid & 63;
    const int w    = tid >> 6;
    const int g    = lane >> 4;
    const int l15  = lane & 15;
    const int m0   = blockIdx.y * 128;
    const int n0   = blockIdx.x * 128;
    const int wm   = (w >> 1) * 64;
    const int wn   = (w & 1) * 64;

    f32x4 acc[4][4];
#pragma unroll
    for (int i = 0; i < 4; i++)
#pragma unroll
        for (int j = 0; j < 4; j++) acc[i][j] = (f32x4){0.f, 0.f, 0.f, 0.f};

    const int c0 = tid, c1 = tid + 256;
    const int rowA0 = c0 >> 2, colA0 = (c0 & 3) * 8;
    const int rowA1 = c1 >> 2, colA1 = (c1 & 3) * 8;

    for (int k0 = 0; k0 < K; k0 += 32) {
        __syncthreads();
        __builtin_amdgcn_global_load_lds(TO_GLOBAL(A + (size_t)(m0 + rowA0) * K + k0 + colA0),
                                         TO_LDS(&Ash[c0 * 8]), 16, 0, 0);
        __builtin_amdgcn_global_load_lds(TO_GLOBAL(A + (size_t)(m0 + rowA1) * K + k0 + colA1),
                                         TO_LDS(&Ash[c1 * 8]), 16, 0, 0);
        __builtin_amdgcn_global_load_lds(TO_GLOBAL(Bw + (size_t)(n0 + rowA0) * K + k0 + colA0),
                                         TO_LDS(&Bsh[c0 * 8]), 16, 0, 0);
        __builtin_amdgcn_global_load_lds(TO_GLOBAL(Bw + (size_t)(n0 + rowA1) * K + k0 + colA1),
                                         TO_LDS(&Bsh[c1 * 8]), 16, 0, 0);
        __syncthreads();

        bfx8 af[4], bfr[4];
#pragma unroll
        for (int mi = 0; mi < 4; mi++)
            af[mi] = *reinterpret_cast<const bfx8*>(&Ash[(wm + mi * 16 + l15) * 32 + g * 8]);
#pragma unroll
        for (int ni = 0; ni < 4; ni++)
            bfr[ni] = *reinterpret_cast<const bfx8*>(&Bsh[(wn + ni * 16 + l15) * 32 + g * 8]);
#pragma unroll
        for (int mi = 0; mi < 4; mi++)
#pragma unroll
            for (int ni = 0; ni < 4; ni++)
                acc[mi][ni] = __builtin_amdgcn_mfma_f32_16x16x32_bf16(af[mi], bfr[ni],
                                                                     acc[mi][ni], 0, 0, 0);
    }

#pragma unroll
    for (int mi = 0; mi < 4; mi++) {
#pragma unroll
        for (int ni = 0; ni < 4; ni++) {
            const int col = n0 + wn + ni * 16 + l15;
            const float bv = bias[col];
#pragma unroll
            for (int r = 0; r < 4; r++) {
                const int row = m0 + wm + mi * 16 + g * 4 + r;
                store_out(&C[(size_t)row * N + col], (acc[mi][ni][r] + bv) * scale);
            }
        }
    }
}

// ------------------------------------------------- V transpose: [bs][d] -> [d'][s]
// In: V [4096][2048] bf16 (row = b*2048+s, col = h*128+dh)
// Out: Vt [2][2048][2048]  (flat idx = (b*2048 + h*128 + dh)*2048 + s)
__global__ __launch_bounds__(256) void transpose_v(const unsigned short* __restrict__ V,
                                                   unsigned short* __restrict__ Vt) {
    __shared__ unsigned short tile[64][72];
    const int tid = threadIdx.x;
    const int r0 = blockIdx.y * 64;          // token-tile base
    const int c0 = blockIdx.x * 64;          // model-dim tile base
    const int b = r0 >> 11, sbase = r0 & 2047;
#pragma unroll
    for (int i = 0; i < 2; i++) {
        const int row = tid >> 2;
        const int ch  = (tid & 3) + 4 * i;
        bfx8 v = *reinterpret_cast<const bfx8*>(V + (size_t)(r0 + row) * 2048 + c0 + ch * 8);
        *reinterpret_cast<bfx8*>(&tile[row][ch * 8]) = v;
    }
    __syncthreads();
    const int dh  = tid & 63;
    const int s_l = (tid >> 6) * 16;
    unsigned short* dst = Vt + (size_t)(b * 2048 + c0 + dh) * 2048 + sbase + s_l;
#pragma unroll
    for (int half = 0; half < 2; half++) {
        bfx8 o;
#pragma unroll
        for (int j = 0; j < 8; j++) o[j] = (short)tile[s_l + half * 8 + j][dh];
        *reinterpret_cast<bfx8*>(dst + half * 8) = o;
    }
}

// ------------------------------------------------------------ flash attention
// Q,K,O: [B][S][H][dh] bf16 row-major over D. Vt: [bh][dh][s].
// 4 waves/block, each wave owns 16 q-rows independently. KVBLK=64. No barriers.
#define SLEN 2048
#define DMODEL 2048

__global__ __launch_bounds__(256) void attn_kernel(
    const unsigned short* __restrict__ Q, const unsigned short* __restrict__ Kp,
    const unsigned short* __restrict__ Vt, unsigned short* __restrict__ O) {
    __shared__ __align__(16) unsigned short Psh[4096];   // 1024 per wave

    const int tid  = threadIdx.x;
    const int lane = tid & 63;
    const int w    = tid >> 6;
    const int g    = lane >> 4;
    const int l15  = lane & 15;
    const int bh   = blockIdx.x;
    const int b    = bh >> 4, h = bh & 15;
    const int qtile = gridDim.y - 1 - blockIdx.y;   // heavy tiles dispatch first
    const int q0   = qtile * 64;
    const int wq0  = q0 + w * 16;

    const size_t bhbase = (size_t)b * SLEN * DMODEL + (size_t)h * 128;
    const size_t vtbase = (size_t)bh * 128 * SLEN;

    // Q fragments (A operand: row = l15, k = d contiguous)
    const int qrow = wq0 + l15;
    bfx8 qf[4];
#pragma unroll
    for (int c = 0; c < 4; c++)
        qf[c] = *reinterpret_cast<const bfx8*>(Q + bhbase + (size_t)qrow * DMODEL + c * 32 + g * 8);

    f32x4 oacc[8];
#pragma unroll
    for (int i = 0; i < 8; i++) oacc[i] = (f32x4){0.f, 0.f, 0.f, 0.f};
    float m_run[4] = {-1e30f, -1e30f, -1e30f, -1e30f};
    float l_run[4] = {0.f, 0.f, 0.f, 0.f};

    unsigned short* Pw = &Psh[w * 1024];
    const int khi_b = l15 >> 3, klo = l15 & 7;

    for (int t = 0; t <= qtile; t++) {
        const int kb = t * 64;
        const bool last = (t == qtile);
        f32x4 sacc[4];
#pragma unroll
        for (int kt = 0; kt < 4; kt++) {
            if (last && kt > w) {
                sacc[kt] = (f32x4){-1e30f, -1e30f, -1e30f, -1e30f};
                continue;
            }
            sacc[kt] = (f32x4){0.f, 0.f, 0.f, 0.f};
            const unsigned short* kr =
                Kp + bhbase + (size_t)(kb + kt * 16 + l15) * DMODEL + g * 8;
#pragma unroll
            for (int c = 0; c < 4; c++) {
                bfx8 kf = *reinterpret_cast<const bfx8*>(kr + c * 32);
                sacc[kt] = __builtin_amdgcn_mfma_f32_16x16x32_bf16(qf[c], kf, sacc[kt], 0, 0, 0);
            }
        }
        if (last) {
#pragma unroll
            for (int kt = 0; kt < 4; kt++) {
                if (kt > w) continue;
#pragma unroll
                for (int r = 0; r < 4; r++)
                    if (kt * 16 + l15 > w * 16 + g * 4 + r) sacc[kt][r] = -1e30f;
            }
        }
        // ---- online softmax (C/D layout: col=l15=key, row=g*4+r=q)
#pragma unroll
        for (int r = 0; r < 4; r++) {
            float mx = fmaxf(fmaxf(sacc[0][r], sacc[1][r]), fmaxf(sacc[2][r], sacc[3][r]));
#pragma unroll
            for (int s = 1; s < 16; s <<= 1) mx = fmaxf(mx, __shfl_xor(mx, s));
            const float mnew = fmaxf(m_run[r], mx);
            const float corr = __expf(m_run[r] - mnew);
            const float p0 = __expf(sacc[0][r] - mnew);
            const float p1 = __expf(sacc[1][r] - mnew);
            const float p2 = __expf(sacc[2][r] - mnew);
            const float p3 = __expf(sacc[3][r] - mnew);
            float ps = (p0 + p1) + (p2 + p3);
#pragma unroll
            for (int s = 1; s < 16; s <<= 1) ps += __shfl_xor(ps, s);
            m_run[r] = mnew;
            l_run[r] = l_run[r] * corr + ps;
            const int ql = g * 4 + r;
            const int swz = ql & 7;
            // XOR-swizzled P: elem(q,k) = q*64 + (((k>>3)^(q&7))<<3) + (k&7)
            Pw[ql * 64 + (((khi_b + 0) ^ swz) << 3) + klo] = f2bf(p0);
            Pw[ql * 64 + (((khi_b + 2) ^ swz) << 3) + klo] = f2bf(p1);
            Pw[ql * 64 + (((khi_b + 4) ^ swz) << 3) + klo] = f2bf(p2);
            Pw[ql * 64 + (((khi_b + 6) ^ swz) << 3) + klo] = f2bf(p3);
#pragma unroll
            for (int ni = 0; ni < 8; ni++) oacc[ni][r] *= corr;
        }
        // ---- O += P V  (B operand from Vt: col=l15=d, k=key contiguous)
#pragma unroll
        for (int ks = 0; ks < 2; ks++) {
            if (last && ks * 32 > w * 16 + 15) break;
            bfx8 pa = *reinterpret_cast<const bfx8*>(
                Pw + l15 * 64 + (((ks * 4 + g) ^ (l15 & 7)) << 3));
            const unsigned short* vr =
                Vt + vtbase + (size_t)l15 * SLEN + kb + ks * 32 + g * 8;
#pragma unroll
            for (int ni = 0; ni < 8; ni++) {
                bfx8 vb = *reinterpret_cast<const bfx8*>(vr + (size_t)ni * 16 * SLEN);
                oacc[ni] = __builtin_amdgcn_mfma_f32_16x16x32_bf16(pa, vb, oacc[ni], 0, 0, 0);
            }
        }
    }

    // ---- normalize + store
#pragma unroll
    for (int r = 0; r < 4; r++) {
        const float inv = 1.0f / l_run[r];
        const int q = wq0 + g * 4 + r;
#pragma unroll
        for (int ni = 0; ni < 8; ni++)
            O[bhbase + (size_t)q * DMODEL + ni * 16 + l15] = f2bf(oacc[ni][r] * inv);
    }
}

// ---------------------------------------------------------------------------
extern "C" void kernel_launch(void* const* d_in, const int* in_sizes, int n_in,
                              void* d_out, int out_size, void* d_ws, size_t ws_size,
                              hipStream_t stream) {
    const float* X  = (const float*)d_in[0];
    const float* Wq = (const float*)d_in[1];
    const float* bq = (const float*)d_in[2];
    const float* Wk = (const float*)d_in[3];
    const float* bk = (const float*)d_in[4];
    const float* Wv = (const float*)d_in[5];
    const float* bv = (const float*)d_in[6];
    const float* Wo = (const float*)d_in[7];
    const float* bo = (const float*)d_in[8];
    float* out = (float*)d_out;

    // workspace layout (bf16 elements): Q | K | Vt | X(->attn O) | Wstage
    unsigned short* ws  = (unsigned short*)d_ws;
    unsigned short* Qb  = ws;
    unsigned short* Kb  = ws + 8388608;
    unsigned short* Vtb = ws + 16777216;
    unsigned short* XOb = ws + 25165824;   // X bf16, reused as attention output
    unsigned short* Wb  = ws + 33554432;   // weight staging
    unsigned short* Vstage = (unsigned short*)d_out;  // V row-major staging (16MB of 32MB)

    const float qk_scale = 0.29730177875068026f;  // 128^(-1/4)

    const dim3 cb(256);
    const dim3 gg(16, 32), gb(256);

    cast_bf16_kernel<<<dim3(2048), cb, 0, stream>>>(X, XOb, 2097152);

    cast_bf16_kernel<<<dim3(1024), cb, 0, stream>>>(Wq, Wb, 1048576);
    gemm_bt<unsigned short><<<gg, gb, 0, stream>>>(XOb, Wb, bq, Qb, 4096, 2048, 2048, qk_scale);

    cast_bf16_kernel<<<dim3(1024), cb, 0, stream>>>(Wk, Wb, 1048576);
    gemm_bt<unsigned short><<<gg, gb, 0, stream>>>(XOb, Wb, bk, Kb, 4096, 2048, 2048, qk_scale);

    cast_bf16_kernel<<<dim3(1024), cb, 0, stream>>>(Wv, Wb, 1048576);
    gemm_bt<unsigned short><<<gg, gb, 0, stream>>>(XOb, Wb, bv, Vstage, 4096, 2048, 2048, 1.0f);
    transpose_v<<<dim3(32, 64), cb, 0, stream>>>(Vstage, Vtb);

    attn_kernel<<<dim3(32, 32), gb, 0, stream>>>(Qb, Kb, Vtb, XOb);

    cast_bf16_kernel<<<dim3(1024), cb, 0, stream>>>(Wo, Wb, 1048576);
    gemm_bt<float><<<gg, gb, 0, stream>>>(XOb, Wb, bo, out, 4096, 2048, 2048, 1.0f);
}

// Round 3
// 503.046 us; speedup vs baseline: 1.3345x; 1.0503x over previous
//
#include <hip/hip_runtime.h>

// ---------------------------------------------------------------------------
// MultiHeadedDotProductSelfAttention: B=2, S=2048, D=2048, H=16, dh=128
// R2: attention -> 1-wave blocks (64 thr), 4096 blocks, K-tile register
// prefetch (16 loads in flight), uniform branch-light body. GEMMs unchanged.
// ---------------------------------------------------------------------------

typedef __attribute__((ext_vector_type(8))) short bfx8;
typedef __attribute__((ext_vector_type(4))) float f32x4;

#define TO_GLOBAL(p) ((const __attribute__((address_space(1))) void*)(p))
#define TO_LDS(p)    ((__attribute__((address_space(3))) void*)(p))

__device__ __forceinline__ unsigned short f2bf(float f) {
    unsigned int u = __float_as_uint(f);
    u += 0x7FFFu + ((u >> 16) & 1u);          // round-to-nearest-even
    return (unsigned short)(u >> 16);
}

__device__ __forceinline__ void store_out(unsigned short* p, float v) { *p = f2bf(v); }
__device__ __forceinline__ void store_out(float* p, float v) { *p = v; }

// ---------------------------------------------------------------- cast kernel
__global__ void cast_bf16_kernel(const float* __restrict__ x,
                                 unsigned short* __restrict__ y, int n4) {
    int i = blockIdx.x * blockDim.x + threadIdx.x;
    int st = gridDim.x * blockDim.x;
    for (; i < n4; i += st) {
        float4 v = reinterpret_cast<const float4*>(x)[i];
        ushort4 o;
        o.x = f2bf(v.x); o.y = f2bf(v.y); o.z = f2bf(v.z); o.w = f2bf(v.w);
        reinterpret_cast<ushort4*>(y)[i] = o;
    }
}

// ------------------------------------------------------- GEMM: C = (A*B^T+b)*s
template <typename OUT>
__global__ __launch_bounds__(256) void gemm_bt(
    const unsigned short* __restrict__ A, const unsigned short* __restrict__ Bw,
    const float* __restrict__ bias, OUT* __restrict__ C,
    int M, int N, int K, float scale) {
    __shared__ __align__(16) unsigned short Ash[128 * 32];
    __shared__ __align__(16) unsigned short Bsh[128 * 32];

    const int tid  = threadIdx.x;
    const int lane = tid & 63;
    const int w    = tid >> 6;
    const int g    = lane >> 4;
    const int l15  = lane & 15;
    const int m0   = blockIdx.y * 128;
    const int n0   = blockIdx.x * 128;
    const int wm   = (w >> 1) * 64;
    const int wn   = (w & 1) * 64;

    f32x4 acc[4][4];
#pragma unroll
    for (int i = 0; i < 4; i++)
#pragma unroll
        for (int j = 0; j < 4; j++) acc[i][j] = (f32x4){0.f, 0.f, 0.f, 0.f};

    const int c0 = tid, c1 = tid + 256;
    const int rowA0 = c0 >> 2, colA0 = (c0 & 3) * 8;
    const int rowA1 = c1 >> 2, colA1 = (c1 & 3) * 8;

    for (int k0 = 0; k0 < K; k0 += 32) {
        __syncthreads();
        __builtin_amdgcn_global_load_lds(TO_GLOBAL(A + (size_t)(m0 + rowA0) * K + k0 + colA0),
                                         TO_LDS(&Ash[c0 * 8]), 16, 0, 0);
        __builtin_amdgcn_global_load_lds(TO_GLOBAL(A + (size_t)(m0 + rowA1) * K + k0 + colA1),
                                         TO_LDS(&Ash[c1 * 8]), 16, 0, 0);
        __builtin_amdgcn_global_load_lds(TO_GLOBAL(Bw + (size_t)(n0 + rowA0) * K + k0 + colA0),
                                         TO_LDS(&Bsh[c0 * 8]), 16, 0, 0);
        __builtin_amdgcn_global_load_lds(TO_GLOBAL(Bw + (size_t)(n0 + rowA1) * K + k0 + colA1),
                                         TO_LDS(&Bsh[c1 * 8]), 16, 0, 0);
        __syncthreads();

        bfx8 af[4], bfr[4];
#pragma unroll
        for (int mi = 0; mi < 4; mi++)
            af[mi] = *reinterpret_cast<const bfx8*>(&Ash[(wm + mi * 16 + l15) * 32 + g * 8]);
#pragma unroll
        for (int ni = 0; ni < 4; ni++)
            bfr[ni] = *reinterpret_cast<const bfx8*>(&Bsh[(wn + ni * 16 + l15) * 32 + g * 8]);
#pragma unroll
        for (int mi = 0; mi < 4; mi++)
#pragma unroll
            for (int ni = 0; ni < 4; ni++)
                acc[mi][ni] = __builtin_amdgcn_mfma_f32_16x16x32_bf16(af[mi], bfr[ni],
                                                                     acc[mi][ni], 0, 0, 0);
    }

#pragma unroll
    for (int mi = 0; mi < 4; mi++) {
#pragma unroll
        for (int ni = 0; ni < 4; ni++) {
            const int col = n0 + wn + ni * 16 + l15;
            const float bv = bias[col];
#pragma unroll
            for (int r = 0; r < 4; r++) {
                const int row = m0 + wm + mi * 16 + g * 4 + r;
                store_out(&C[(size_t)row * N + col], (acc[mi][ni][r] + bv) * scale);
            }
        }
    }
}

// ------------------------------------------------- V transpose: [bs][d] -> [d'][s]
__global__ __launch_bounds__(256) void transpose_v(const unsigned short* __restrict__ V,
                                                   unsigned short* __restrict__ Vt) {
    __shared__ unsigned short tile[64][72];
    const int tid = threadIdx.x;
    const int r0 = blockIdx.y * 64;          // token-tile base
    const int c0 = blockIdx.x * 64;          // model-dim tile base
    const int b = r0 >> 11, sbase = r0 & 2047;
#pragma unroll
    for (int i = 0; i < 2; i++) {
        const int row = tid >> 2;
        const int ch  = (tid & 3) + 4 * i;
        bfx8 v = *reinterpret_cast<const bfx8*>(V + (size_t)(r0 + row) * 2048 + c0 + ch * 8);
        *reinterpret_cast<bfx8*>(&tile[row][ch * 8]) = v;
    }
    __syncthreads();
    const int dh  = tid & 63;
    const int s_l = (tid >> 6) * 16;
    unsigned short* dst = Vt + (size_t)(b * 2048 + c0 + dh) * 2048 + sbase + s_l;
#pragma unroll
    for (int half = 0; half < 2; half++) {
        bfx8 o;
#pragma unroll
        for (int j = 0; j < 8; j++) o[j] = (short)tile[s_l + half * 8 + j][dh];
        *reinterpret_cast<bfx8*>(dst + half * 8) = o;
    }
}

// ------------------------------------------------------------ flash attention
// Q,K,O: [B][S][H][dh] bf16. Vt: [bh][dh][s]. 1 wave per block, 16 q-rows.
// KVBLK=64, K-tile register prefetch, P via per-block LDS (intra-wave).
#define SLEN 2048
#define DMODEL 2048

__global__ __launch_bounds__(64, 3) void attn_kernel(
    const unsigned short* __restrict__ Q, const unsigned short* __restrict__ Kp,
    const unsigned short* __restrict__ Vt, unsigned short* __restrict__ O) {
    __shared__ __align__(16) unsigned short Pw[1024];

    const int lane = threadIdx.x;
    const int g    = lane >> 4;
    const int l15  = lane & 15;
    const int bh   = blockIdx.x;
    const int b    = bh >> 4, h = bh & 15;
    const int qt   = gridDim.y - 1 - blockIdx.y;   // heavy q-tiles dispatch first
    const int q0   = qt * 16;

    const size_t bhbase = (size_t)b * SLEN * DMODEL + (size_t)h * 128;
    const size_t vtbase = (size_t)bh * 128 * SLEN;

    // Q fragments (A operand: row = l15, k = d contiguous)
    bfx8 qf[4];
#pragma unroll
    for (int c = 0; c < 4; c++)
        qf[c] = *reinterpret_cast<const bfx8*>(
            Q + bhbase + (size_t)(q0 + l15) * DMODEL + c * 32 + g * 8);

    f32x4 oacc[8];
#pragma unroll
    for (int i = 0; i < 8; i++) oacc[i] = (f32x4){0.f, 0.f, 0.f, 0.f};
    float m_run[4] = {-1e30f, -1e30f, -1e30f, -1e30f};
    float l_run[4] = {0.f, 0.f, 0.f, 0.f};

    const int khi_b = l15 >> 3, klo = l15 & 7;
    const int nkv = qt / 4 + 1;

    for (int t = 0; t < nkv; t++) {
        const int kb = t * 64;
        // ---- batch-load the whole K tile into registers (16 loads in flight)
        bfx8 kf[4][4];
        const unsigned short* krow0 = Kp + bhbase + (size_t)(kb + l15) * DMODEL + g * 8;
#pragma unroll
        for (int kt = 0; kt < 4; kt++)
#pragma unroll
            for (int c = 0; c < 4; c++)
                kf[kt][c] = *reinterpret_cast<const bfx8*>(
                    krow0 + (size_t)kt * 16 * DMODEL + c * 32);

        f32x4 sacc[4];
#pragma unroll
        for (int kt = 0; kt < 4; kt++) {
            sacc[kt] = (f32x4){0.f, 0.f, 0.f, 0.f};
#pragma unroll
            for (int c = 0; c < 4; c++)
                sacc[kt] = __builtin_amdgcn_mfma_f32_16x16x32_bf16(qf[c], kf[kt][c],
                                                                   sacc[kt], 0, 0, 0);
        }
        // ---- causal mask (only the diagonal tile)
        if (t == nkv - 1) {
#pragma unroll
            for (int kt = 0; kt < 4; kt++)
#pragma unroll
                for (int r = 0; r < 4; r++)
                    if (kb + kt * 16 + l15 > q0 + g * 4 + r) sacc[kt][r] = -1e30f;
        }
        // ---- online softmax (C/D: col=l15=key, row=g*4+r=q)
#pragma unroll
        for (int r = 0; r < 4; r++) {
            float mx = fmaxf(fmaxf(sacc[0][r], sacc[1][r]), fmaxf(sacc[2][r], sacc[3][r]));
#pragma unroll
            for (int s = 1; s < 16; s <<= 1) mx = fmaxf(mx, __shfl_xor(mx, s));
            const float mnew = fmaxf(m_run[r], mx);
            const float corr = __expf(m_run[r] - mnew);
            const float p0 = __expf(sacc[0][r] - mnew);
            const float p1 = __expf(sacc[1][r] - mnew);
            const float p2 = __expf(sacc[2][r] - mnew);
            const float p3 = __expf(sacc[3][r] - mnew);
            float ps = (p0 + p1) + (p2 + p3);
#pragma unroll
            for (int s = 1; s < 16; s <<= 1) ps += __shfl_xor(ps, s);
            m_run[r] = mnew;
            l_run[r] = l_run[r] * corr + ps;
            const int ql = g * 4 + r;
            const int swz = ql & 7;
            // XOR-swizzled P: elem(q,k) = q*64 + (((k>>3)^(q&7))<<3) + (k&7)
            Pw[ql * 64 + (((khi_b + 0) ^ swz) << 3) + klo] = f2bf(p0);
            Pw[ql * 64 + (((khi_b + 2) ^ swz) << 3) + klo] = f2bf(p1);
            Pw[ql * 64 + (((khi_b + 4) ^ swz) << 3) + klo] = f2bf(p2);
            Pw[ql * 64 + (((khi_b + 6) ^ swz) << 3) + klo] = f2bf(p3);
#pragma unroll
            for (int ni = 0; ni < 8; ni++) oacc[ni][r] *= corr;
        }
        // ---- O += P V  (B operand from Vt: col=l15=d, k=key contiguous)
#pragma unroll
        for (int ks = 0; ks < 2; ks++) {
            // issue V loads first (independent of P)
            const unsigned short* vr =
                Vt + vtbase + (size_t)l15 * SLEN + kb + ks * 32 + g * 8;
            bfx8 vb[8];
#pragma unroll
            for (int ni = 0; ni < 8; ni++)
                vb[ni] = *reinterpret_cast<const bfx8*>(vr + (size_t)ni * 16 * SLEN);
            bfx8 pa = *reinterpret_cast<const bfx8*>(
                Pw + l15 * 64 + (((ks * 4 + g) ^ (l15 & 7)) << 3));
#pragma unroll
            for (int ni = 0; ni < 8; ni++)
                oacc[ni] = __builtin_amdgcn_mfma_f32_16x16x32_bf16(pa, vb[ni],
                                                                   oacc[ni], 0, 0, 0);
        }
    }

    // ---- normalize + store
#pragma unroll
    for (int r = 0; r < 4; r++) {
        const float inv = 1.0f / l_run[r];
        const int q = q0 + g * 4 + r;
#pragma unroll
        for (int ni = 0; ni < 8; ni++)
            O[bhbase + (size_t)q * DMODEL + ni * 16 + l15] = f2bf(oacc[ni][r] * inv);
    }
}

// ---------------------------------------------------------------------------
extern "C" void kernel_launch(void* const* d_in, const int* in_sizes, int n_in,
                              void* d_out, int out_size, void* d_ws, size_t ws_size,
                              hipStream_t stream) {
    const float* X  = (const float*)d_in[0];
    const float* Wq = (const float*)d_in[1];
    const float* bq = (const float*)d_in[2];
    const float* Wk = (const float*)d_in[3];
    const float* bk = (const float*)d_in[4];
    const float* Wv = (const float*)d_in[5];
    const float* bv = (const float*)d_in[6];
    const float* Wo = (const float*)d_in[7];
    const float* bo = (const float*)d_in[8];
    float* out = (float*)d_out;

    // workspace layout (bf16 elements): Q | K | Vt | X(->attn O) | Wstage
    unsigned short* ws  = (unsigned short*)d_ws;
    unsigned short* Qb  = ws;
    unsigned short* Kb  = ws + 8388608;
    unsigned short* Vtb = ws + 16777216;
    unsigned short* XOb = ws + 25165824;   // X bf16, reused as attention output
    unsigned short* Wb  = ws + 33554432;   // weight staging
    unsigned short* Vstage = (unsigned short*)d_out;  // V row-major staging

    const float qk_scale = 0.29730177875068026f;  // 128^(-1/4)

    const dim3 cb(256);
    const dim3 gg(16, 32), gb(256);

    cast_bf16_kernel<<<dim3(2048), cb, 0, stream>>>(X, XOb, 2097152);

    cast_bf16_kernel<<<dim3(1024), cb, 0, stream>>>(Wq, Wb, 1048576);
    gemm_bt<unsigned short><<<gg, gb, 0, stream>>>(XOb, Wb, bq, Qb, 4096, 2048, 2048, qk_scale);

    cast_bf16_kernel<<<dim3(1024), cb, 0, stream>>>(Wk, Wb, 1048576);
    gemm_bt<unsigned short><<<gg, gb, 0, stream>>>(XOb, Wb, bk, Kb, 4096, 2048, 2048, qk_scale);

    cast_bf16_kernel<<<dim3(1024), cb, 0, stream>>>(Wv, Wb, 1048576);
    gemm_bt<unsigned short><<<gg, gb, 0, stream>>>(XOb, Wb, bv, Vstage, 4096, 2048, 2048, 1.0f);
    transpose_v<<<dim3(32, 64), cb, 0, stream>>>(Vstage, Vtb);

    attn_kernel<<<dim3(32, 128), dim3(64), 0, stream>>>(Qb, Kb, Vtb, XOb);

    cast_bf16_kernel<<<dim3(1024), cb, 0, stream>>>(Wo, Wb, 1048576);
    gemm_bt<float><<<gg, gb, 0, stream>>>(XOb, Wb, bo, out, 4096, 2048, 2048, 1.0f);
}

// Round 4
// 373.022 us; speedup vs baseline: 1.7997x; 1.3486x over previous
//
#include <hip/hip_runtime.h>

// ---------------------------------------------------------------------------
// MultiHeadedDotProductSelfAttention: B=2, S=2048, D=2048, H=16, dh=128
// R4: attention -> 4-wave blocks, 128 q-rows share LDS-staged K/V tiles
// (global_load_lds + XOR-swizzle source/read), KVBLK=64. GEMMs unchanged.
// ---------------------------------------------------------------------------

typedef __attribute__((ext_vector_type(8))) short bfx8;
typedef __attribute__((ext_vector_type(4))) float f32x4;

#define TO_GLOBAL(p) ((const __attribute__((address_space(1))) void*)(p))
#define TO_LDS(p)    ((__attribute__((address_space(3))) void*)(p))

__device__ __forceinline__ unsigned short f2bf(float f) {
    unsigned int u = __float_as_uint(f);
    u += 0x7FFFu + ((u >> 16) & 1u);          // round-to-nearest-even
    return (unsigned short)(u >> 16);
}

__device__ __forceinline__ void store_out(unsigned short* p, float v) { *p = f2bf(v); }
__device__ __forceinline__ void store_out(float* p, float v) { *p = v; }

// ---------------------------------------------------------------- cast kernel
__global__ void cast_bf16_kernel(const float* __restrict__ x,
                                 unsigned short* __restrict__ y, int n4) {
    int i = blockIdx.x * blockDim.x + threadIdx.x;
    int st = gridDim.x * blockDim.x;
    for (; i < n4; i += st) {
        float4 v = reinterpret_cast<const float4*>(x)[i];
        ushort4 o;
        o.x = f2bf(v.x); o.y = f2bf(v.y); o.z = f2bf(v.z); o.w = f2bf(v.w);
        reinterpret_cast<ushort4*>(y)[i] = o;
    }
}

// ------------------------------------------------------- GEMM: C = (A*B^T+b)*s
template <typename OUT>
__global__ __launch_bounds__(256) void gemm_bt(
    const unsigned short* __restrict__ A, const unsigned short* __restrict__ Bw,
    const float* __restrict__ bias, OUT* __restrict__ C,
    int M, int N, int K, float scale) {
    __shared__ __align__(16) unsigned short Ash[128 * 32];
    __shared__ __align__(16) unsigned short Bsh[128 * 32];

    const int tid  = threadIdx.x;
    const int lane = tid & 63;
    const int w    = tid >> 6;
    const int g    = lane >> 4;
    const int l15  = lane & 15;
    const int m0   = blockIdx.y * 128;
    const int n0   = blockIdx.x * 128;
    const int wm   = (w >> 1) * 64;
    const int wn   = (w & 1) * 64;

    f32x4 acc[4][4];
#pragma unroll
    for (int i = 0; i < 4; i++)
#pragma unroll
        for (int j = 0; j < 4; j++) acc[i][j] = (f32x4){0.f, 0.f, 0.f, 0.f};

    const int c0 = tid, c1 = tid + 256;
    const int rowA0 = c0 >> 2, colA0 = (c0 & 3) * 8;
    const int rowA1 = c1 >> 2, colA1 = (c1 & 3) * 8;

    for (int k0 = 0; k0 < K; k0 += 32) {
        __syncthreads();
        __builtin_amdgcn_global_load_lds(TO_GLOBAL(A + (size_t)(m0 + rowA0) * K + k0 + colA0),
                                         TO_LDS(&Ash[c0 * 8]), 16, 0, 0);
        __builtin_amdgcn_global_load_lds(TO_GLOBAL(A + (size_t)(m0 + rowA1) * K + k0 + colA1),
                                         TO_LDS(&Ash[c1 * 8]), 16, 0, 0);
        __builtin_amdgcn_global_load_lds(TO_GLOBAL(Bw + (size_t)(n0 + rowA0) * K + k0 + colA0),
                                         TO_LDS(&Bsh[c0 * 8]), 16, 0, 0);
        __builtin_amdgcn_global_load_lds(TO_GLOBAL(Bw + (size_t)(n0 + rowA1) * K + k0 + colA1),
                                         TO_LDS(&Bsh[c1 * 8]), 16, 0, 0);
        __syncthreads();

        bfx8 af[4], bfr[4];
#pragma unroll
        for (int mi = 0; mi < 4; mi++)
            af[mi] = *reinterpret_cast<const bfx8*>(&Ash[(wm + mi * 16 + l15) * 32 + g * 8]);
#pragma unroll
        for (int ni = 0; ni < 4; ni++)
            bfr[ni] = *reinterpret_cast<const bfx8*>(&Bsh[(wn + ni * 16 + l15) * 32 + g * 8]);
#pragma unroll
        for (int mi = 0; mi < 4; mi++)
#pragma unroll
            for (int ni = 0; ni < 4; ni++)
                acc[mi][ni] = __builtin_amdgcn_mfma_f32_16x16x32_bf16(af[mi], bfr[ni],
                                                                     acc[mi][ni], 0, 0, 0);
    }

#pragma unroll
    for (int mi = 0; mi < 4; mi++) {
#pragma unroll
        for (int ni = 0; ni < 4; ni++) {
            const int col = n0 + wn + ni * 16 + l15;
            const float bv = bias[col];
#pragma unroll
            for (int r = 0; r < 4; r++) {
                const int row = m0 + wm + mi * 16 + g * 4 + r;
                store_out(&C[(size_t)row * N + col], (acc[mi][ni][r] + bv) * scale);
            }
        }
    }
}

// ------------------------------------------------- V transpose: [bs][d] -> [d'][s]
__global__ __launch_bounds__(256) void transpose_v(const unsigned short* __restrict__ V,
                                                   unsigned short* __restrict__ Vt) {
    __shared__ unsigned short tile[64][72];
    const int tid = threadIdx.x;
    const int r0 = blockIdx.y * 64;          // token-tile base
    const int c0 = blockIdx.x * 64;          // model-dim tile base
    const int b = r0 >> 11, sbase = r0 & 2047;
#pragma unroll
    for (int i = 0; i < 2; i++) {
        const int row = tid >> 2;
        const int ch  = (tid & 3) + 4 * i;
        bfx8 v = *reinterpret_cast<const bfx8*>(V + (size_t)(r0 + row) * 2048 + c0 + ch * 8);
        *reinterpret_cast<bfx8*>(&tile[row][ch * 8]) = v;
    }
    __syncthreads();
    const int dh  = tid & 63;
    const int s_l = (tid >> 6) * 16;
    unsigned short* dst = Vt + (size_t)(b * 2048 + c0 + dh) * 2048 + sbase + s_l;
#pragma unroll
    for (int half = 0; half < 2; half++) {
        bfx8 o;
#pragma unroll
        for (int j = 0; j < 8; j++) o[j] = (short)tile[s_l + half * 8 + j][dh];
        *reinterpret_cast<bfx8*>(dst + half * 8) = o;
    }
}

// ------------------------------------------------------------ flash attention
// Q,K,O: [B][S][H][dh] bf16. Vt: [bh][dh][s]. 4 waves/block, 128 q-rows/block
// (32 per wave, two 16-row fragments). KVBLK=64. K/V staged in LDS via
// global_load_lds (linear dest) with XOR-swizzled global source; ds_read uses
// the same XOR -> conflict-free. 2 barriers per tile.
#define SLEN 2048
#define DMODEL 2048

__global__ __launch_bounds__(256) void attn_kernel(
    const unsigned short* __restrict__ Q, const unsigned short* __restrict__ Kp,
    const unsigned short* __restrict__ Vt, unsigned short* __restrict__ O) {
    __shared__ __align__(16) unsigned short Ksh[64 * 128];   // [row][d], swizzled 16B chunks
    __shared__ __align__(16) unsigned short Vsh[128 * 64];   // [d][key], swizzled 16B chunks
    __shared__ __align__(16) unsigned short Psh[4 * 2048];   // per-wave P (2 qfrags)

    const int tid  = threadIdx.x;
    const int lane = tid & 63;
    const int w    = tid >> 6;
    const int g    = lane >> 4;
    const int l15  = lane & 15;
    const int bh   = blockIdx.x;
    const int b    = bh >> 4, h = bh & 15;
    const int qb   = gridDim.y - 1 - blockIdx.y;   // heavy q-blocks dispatch first
    const int q0   = qb * 128;
    const int q0w  = q0 + w * 32;

    const size_t bhbase = (size_t)b * SLEN * DMODEL + (size_t)h * 128;
    const size_t vtbase = (size_t)bh * 128 * SLEN;

    // Q fragments: 2 x 16 rows (A operand: row = l15, k chunk = g)
    bfx8 qf[2][4];
#pragma unroll
    for (int f = 0; f < 2; f++)
#pragma unroll
        for (int c = 0; c < 4; c++)
            qf[f][c] = *reinterpret_cast<const bfx8*>(
                Q + bhbase + (size_t)(q0w + f * 16 + l15) * DMODEL + c * 32 + g * 8);

    f32x4 oacc[2][8];
#pragma unroll
    for (int f = 0; f < 2; f++)
#pragma unroll
        for (int i = 0; i < 8; i++) oacc[f][i] = (f32x4){0.f, 0.f, 0.f, 0.f};
    float m_run[2][4], l_run[2][4];
#pragma unroll
    for (int f = 0; f < 2; f++)
#pragma unroll
        for (int r = 0; r < 4; r++) { m_run[f][r] = -1e30f; l_run[f][r] = 0.f; }

    unsigned short* Pw = &Psh[w * 2048];
    const int khi_b = l15 >> 3, klo = l15 & 7;
    const int vsw = l15 & 7;
    const int ntile = 2 * qb + 2;

    for (int t = 0; t < ntile; t++) {
        const int kb = t * 64;
        __syncthreads();   // previous tile's LDS reads done
        // ---- stage K [64 rows x 128 d]: linear dest, inverse-swizzled source
#pragma unroll
        for (int i = 0; i < 4; i++) {
            const int c = tid + 256 * i;
            const int row = c >> 4, ch = c & 15;
            __builtin_amdgcn_global_load_lds(
                TO_GLOBAL(Kp + bhbase + (size_t)(kb + row) * DMODEL + ((ch ^ (row & 7)) * 8)),
                TO_LDS(&Ksh[c * 8]), 16, 0, 0);
        }
        // ---- stage V [128 d x 64 keys] from Vt
#pragma unroll
        for (int i = 0; i < 4; i++) {
            const int c = tid + 256 * i;
            const int dr = c >> 3, ch = c & 7;
            __builtin_amdgcn_global_load_lds(
                TO_GLOBAL(Vt + vtbase + (size_t)dr * SLEN + kb + ((ch ^ (dr & 7)) * 8)),
                TO_LDS(&Vsh[c * 8]), 16, 0, 0);
        }
        __syncthreads();   // staging complete (compiler drains vmcnt)

        if (kb <= q0w + 31) {
            // ---- S = Q K^T (both q-fragments share each K fragment)
            f32x4 sacc[2][4];
#pragma unroll
            for (int f = 0; f < 2; f++)
#pragma unroll
                for (int kt = 0; kt < 4; kt++) sacc[f][kt] = (f32x4){0.f, 0.f, 0.f, 0.f};
#pragma unroll
            for (int kt = 0; kt < 4; kt++) {
                const int row = kt * 16 + l15;
#pragma unroll
                for (int c = 0; c < 4; c++) {
                    bfx8 kf = *reinterpret_cast<const bfx8*>(
                        &Ksh[row * 128 + (((c * 4 + g) ^ (row & 7)) * 8)]);
                    sacc[0][kt] = __builtin_amdgcn_mfma_f32_16x16x32_bf16(qf[0][c], kf,
                                                                         sacc[0][kt], 0, 0, 0);
                    sacc[1][kt] = __builtin_amdgcn_mfma_f32_16x16x32_bf16(qf[1][c], kf,
                                                                         sacc[1][kt], 0, 0, 0);
                }
            }
            // ---- causal mask (diagonal tiles only)
            if (kb + 63 > q0w) {
#pragma unroll
                for (int f = 0; f < 2; f++)
#pragma unroll
                    for (int kt = 0; kt < 4; kt++)
#pragma unroll
                        for (int r = 0; r < 4; r++)
                            if (kb + kt * 16 + l15 > q0w + f * 16 + g * 4 + r)
                                sacc[f][kt][r] = -1e30f;
            }
            // ---- online softmax + P write (per q-fragment)
#pragma unroll
            for (int f = 0; f < 2; f++) {
                unsigned short* Pq = Pw + f * 1024;
#pragma unroll
                for (int r = 0; r < 4; r++) {
                    float mx = fmaxf(fmaxf(sacc[f][0][r], sacc[f][1][r]),
                                     fmaxf(sacc[f][2][r], sacc[f][3][r]));
#pragma unroll
                    for (int s = 1; s < 16; s <<= 1) mx = fmaxf(mx, __shfl_xor(mx, s));
                    const float mnew = fmaxf(m_run[f][r], mx);
                    const float corr = __expf(m_run[f][r] - mnew);
                    const float p0 = __expf(sacc[f][0][r] - mnew);
                    const float p1 = __expf(sacc[f][1][r] - mnew);
                    const float p2 = __expf(sacc[f][2][r] - mnew);
                    const float p3 = __expf(sacc[f][3][r] - mnew);
                    float ps = (p0 + p1) + (p2 + p3);
#pragma unroll
                    for (int s = 1; s < 16; s <<= 1) ps += __shfl_xor(ps, s);
                    m_run[f][r] = mnew;
                    l_run[f][r] = l_run[f][r] * corr + ps;
                    const int ql = g * 4 + r;
                    const int swz = ql & 7;
                    Pq[ql * 64 + (((khi_b + 0) ^ swz) << 3) + klo] = f2bf(p0);
                    Pq[ql * 64 + (((khi_b + 2) ^ swz) << 3) + klo] = f2bf(p1);
                    Pq[ql * 64 + (((khi_b + 4) ^ swz) << 3) + klo] = f2bf(p2);
                    Pq[ql * 64 + (((khi_b + 6) ^ swz) << 3) + klo] = f2bf(p3);
#pragma unroll
                    for (int ni = 0; ni < 8; ni++) oacc[f][ni][r] *= corr;
                }
            }
            // ---- O += P V (V fragments shared by both q-fragments)
#pragma unroll
            for (int ks = 0; ks < 2; ks++) {
                bfx8 vb[8];
#pragma unroll
                for (int ni = 0; ni < 8; ni++) {
                    const int d = ni * 16 + l15;
                    vb[ni] = *reinterpret_cast<const bfx8*>(
                        &Vsh[d * 64 + (((ks * 4 + g) ^ vsw) * 8)]);
                }
#pragma unroll
                for (int f = 0; f < 2; f++) {
                    bfx8 pa = *reinterpret_cast<const bfx8*>(
                        Pw + f * 1024 + l15 * 64 + (((ks * 4 + g) ^ vsw) << 3));
#pragma unroll
                    for (int ni = 0; ni < 8; ni++)
                        oacc[f][ni] = __builtin_amdgcn_mfma_f32_16x16x32_bf16(pa, vb[ni],
                                                                              oacc[f][ni], 0, 0, 0);
                }
            }
        }
    }

    // ---- normalize + store
#pragma unroll
    for (int f = 0; f < 2; f++)
#pragma unroll
        for (int r = 0; r < 4; r++) {
            const float inv = 1.0f / l_run[f][r];
            const int q = q0w + f * 16 + g * 4 + r;
#pragma unroll
            for (int ni = 0; ni < 8; ni++)
                O[bhbase + (size_t)q * DMODEL + ni * 16 + l15] = f2bf(oacc[f][ni][r] * inv);
        }
}

// ---------------------------------------------------------------------------
extern "C" void kernel_launch(void* const* d_in, const int* in_sizes, int n_in,
                              void* d_out, int out_size, void* d_ws, size_t ws_size,
                              hipStream_t stream) {
    const float* X  = (const float*)d_in[0];
    const float* Wq = (const float*)d_in[1];
    const float* bq = (const float*)d_in[2];
    const float* Wk = (const float*)d_in[3];
    const float* bk = (const float*)d_in[4];
    const float* Wv = (const float*)d_in[5];
    const float* bv = (const float*)d_in[6];
    const float* Wo = (const float*)d_in[7];
    const float* bo = (const float*)d_in[8];
    float* out = (float*)d_out;

    // workspace layout (bf16 elements): Q | K | Vt | X(->attn O) | Wstage
    unsigned short* ws  = (unsigned short*)d_ws;
    unsigned short* Qb  = ws;
    unsigned short* Kb  = ws + 8388608;
    unsigned short* Vtb = ws + 16777216;
    unsigned short* XOb = ws + 25165824;   // X bf16, reused as attention output
    unsigned short* Wb  = ws + 33554432;   // weight staging
    unsigned short* Vstage = (unsigned short*)d_out;  // V row-major staging

    const float qk_scale = 0.29730177875068026f;  // 128^(-1/4)

    const dim3 cb(256);
    const dim3 gg(16, 32), gb(256);

    cast_bf16_kernel<<<dim3(2048), cb, 0, stream>>>(X, XOb, 2097152);

    cast_bf16_kernel<<<dim3(1024), cb, 0, stream>>>(Wq, Wb, 1048576);
    gemm_bt<unsigned short><<<gg, gb, 0, stream>>>(XOb, Wb, bq, Qb, 4096, 2048, 2048, qk_scale);

    cast_bf16_kernel<<<dim3(1024), cb, 0, stream>>>(Wk, Wb, 1048576);
    gemm_bt<unsigned short><<<gg, gb, 0, stream>>>(XOb, Wb, bk, Kb, 4096, 2048, 2048, qk_scale);

    cast_bf16_kernel<<<dim3(1024), cb, 0, stream>>>(Wv, Wb, 1048576);
    gemm_bt<unsigned short><<<gg, gb, 0, stream>>>(XOb, Wb, bv, Vstage, 4096, 2048, 2048, 1.0f);
    transpose_v<<<dim3(32, 64), cb, 0, stream>>>(Vstage, Vtb);

    attn_kernel<<<dim3(32, 16), gb, 0, stream>>>(Qb, Kb, Vtb, XOb);

    cast_bf16_kernel<<<dim3(1024), cb, 0, stream>>>(Wo, Wb, 1048576);
    gemm_bt<float><<<gg, gb, 0, stream>>>(XOb, Wb, bo, out, 4096, 2048, 2048, 1.0f);
}